// Round 15
// baseline (198.239 us; speedup 1.0000x reference)
//
#include <hip/hip_runtime.h>
#include <hip/hip_bf16.h>

#define N_NODES 100000
#define N_EDGES 3200000
#define CH 32
#define NK 9
#define KTOT 320                                // 288 z + 32 x (root plane)
#define RS 328                                  // padded K stride (bf16) for zlds

#define BNODES 128                              // destination nodes per bucket
#define NBUCK ((N_NODES + BNODES - 1) / BNODES) // 782
#define CURS_PAD 16
#define MAXB 4800                               // mean 4096, wide margin
#define CHE 8192
#define NCHUNK ((N_EDGES + CHE - 1) / CHE)      // 391

typedef __hip_bfloat16 bf16;
typedef unsigned short u16;
typedef __attribute__((ext_vector_type(8))) short bf16x8;
typedef __attribute__((ext_vector_type(4))) float f32x4;

// ---------------------------------------------------------------------------
// Prep: x -> bf16 copy; [weight | root_w^T] -> bf16 B-matrix (MFMA row layout)
// ---------------------------------------------------------------------------
__global__ __launch_bounds__(256) void prep_kernel(const float* __restrict__ x,
                                                   const float* __restrict__ w,
                                                   const float* __restrict__ rw,
                                                   bf16* __restrict__ xb,
                                                   bf16* __restrict__ Bg) {
    int idx = blockIdx.x * 256 + threadIdx.x;
    if (idx < N_NODES * CH / 4) {
        float4 v = ((const float4*)x)[idx];
        union { bf16 h[4]; uint2 u; } pk;
        pk.h[0] = __float2bfloat16(v.x);
        pk.h[1] = __float2bfloat16(v.y);
        pk.h[2] = __float2bfloat16(v.z);
        pk.h[3] = __float2bfloat16(v.w);
        ((uint2*)xb)[idx] = pk.u;
    }
    if (idx < NK * CH * CH) {           // w flat = [k][i][o] = kk*32 + o
        int kk = idx >> 5, o = idx & 31;
        Bg[o * RS + kk] = __float2bfloat16(w[idx]);
    }
    if (idx < CH * CH) {                // rw[o][i]
        int o = idx >> 5, i = idx & 31;
        Bg[o * RS + 288 + i] = __float2bfloat16(rw[idx]);
    }
}

// ---------------------------------------------------------------------------
// Bucket histogram (global), int4-vectorized
// ---------------------------------------------------------------------------
__global__ __launch_bounds__(256) void bhist_kernel(const int* __restrict__ ei_col,
                                                    int* __restrict__ hist) {
    __shared__ int h[NBUCK];
    for (int j = threadIdx.x; j < NBUCK; j += 256) h[j] = 0;
    __syncthreads();
    const int4* c4 = (const int4*)ei_col;
    int stride = gridDim.x * 256;
    for (int e = blockIdx.x * 256 + threadIdx.x; e < N_EDGES / 4; e += stride) {
        int4 v = c4[e];
        atomicAdd(&h[v.x >> 7], 1);
        atomicAdd(&h[v.y >> 7], 1);
        atomicAdd(&h[v.z >> 7], 1);
        atomicAdd(&h[v.w >> 7], 1);
    }
    __syncthreads();
    for (int j = threadIdx.x; j < NBUCK; j += 256)
        if (h[j]) atomicAdd(&hist[j], h[j]);
}

// ---------------------------------------------------------------------------
// Single-block exclusive scan over buckets; writes bstart + sentinel + cursors
// ---------------------------------------------------------------------------
__global__ __launch_bounds__(1024) void bscan_kernel(const int* __restrict__ hist,
                                                     int* __restrict__ bstart,
                                                     int* __restrict__ cursor) {
    __shared__ int s[1024];
    int t = threadIdx.x;
    int a = (2 * t < NBUCK) ? hist[2 * t] : 0;
    int b = (2 * t + 1 < NBUCK) ? hist[2 * t + 1] : 0;
    s[t] = a + b;
    __syncthreads();
    for (int off = 1; off < 1024; off <<= 1) {
        int u = (t >= off) ? s[t - off] : 0;
        __syncthreads();
        s[t] += u;
        __syncthreads();
    }
    int excl = s[t] - (a + b);
    if (2 * t < NBUCK) {
        bstart[2 * t] = excl;
        cursor[2 * t * CURS_PAD] = excl;
    }
    if (2 * t + 1 < NBUCK) {
        bstart[2 * t + 1] = excl + a;
        cursor[(2 * t + 1) * CURS_PAD] = excl + a;
    }
    if (t == 1023) bstart[NBUCK] = s[1023];
}

// ---------------------------------------------------------------------------
// Place, radix-style: per-block histogram -> local scan + global batch alloc
// -> inverse permutation in LDS -> COALESCED write-out (consecutive lanes
// write consecutive addresses within each bucket run).
// Record: {row(17b)|ia(17)|ib(18)|lc(20-26), qa|qb}
// ---------------------------------------------------------------------------
__global__ __launch_bounds__(1024) void place_kernel(const float* __restrict__ pseudo,
                                                     const int* __restrict__ ei,
                                                     int* __restrict__ cursor,
                                                     uint2* __restrict__ edata) {
    __shared__ int h[NBUCK];
    __shared__ int loff[NBUCK];
    __shared__ int gb[NBUCK];
    __shared__ int cur[NBUCK];
    __shared__ unsigned inv[CHE];   // 32 KB: inv[q] = e_local | bucket<<13
    __shared__ int tps[1024];
    int tid = threadIdx.x;
    int c0 = blockIdx.x * CHE;
    int cend = min(c0 + CHE, N_EDGES);
    int sz = cend - c0;

    for (int j = tid; j < NBUCK; j += 1024) h[j] = 0;
    __syncthreads();
    for (int e = c0 + tid; e < cend; e += 1024)
        atomicAdd(&h[ei[N_EDGES + e] >> 7], 1);
    __syncthreads();
    // local exclusive scan over buckets (1024-wide Hillis-Steele)
    int v = (tid < NBUCK) ? h[tid] : 0;
    tps[tid] = v;
    __syncthreads();
    for (int d = 1; d < 1024; d <<= 1) {
        int u = (tid >= d) ? tps[tid - d] : 0;
        __syncthreads();
        tps[tid] += u;
        __syncthreads();
    }
    if (tid < NBUCK) {
        int excl = tps[tid] - v;
        loff[tid] = excl;
        cur[tid] = excl;
        gb[tid] = v ? atomicAdd(&cursor[tid * CURS_PAD], v) : 0;
    }
    __syncthreads();
    // build inverse permutation (LDS scatter)
    for (int e = c0 + tid; e < cend; e += 1024) {
        int b = ei[N_EDGES + e] >> 7;
        int p = atomicAdd(&cur[b], 1);
        inv[p] = (unsigned)(e - c0) | ((unsigned)b << 13);
    }
    __syncthreads();
    // coalesced write-out: slot q -> global gb[b] + (q - loff[b])
    for (int q = tid; q < sz; q += 1024) {
        unsigned u = inv[q];
        int e = c0 + (int)(u & 8191);
        int b = (int)(u >> 13);
        int col = ei[N_EDGES + e];
        int row = ei[e];
        float2 pp = ((const float2*)pseudo)[e];
        float pa = fminf(fmaxf(pp.x, 0.f), 1.f);
        float pb = fminf(fmaxf(pp.y, 0.f), 1.f);
        int ia = pa < 0.5f ? 0 : 1;
        int ib = pb < 0.5f ? 0 : 1;
        float wa1 = 2.f * (pa - 0.5f * (float)ia);
        float wb1 = 2.f * (pb - 0.5f * (float)ib);
        unsigned qa = (unsigned)(wa1 * 65535.f + 0.5f);
        unsigned qb = (unsigned)(wb1 * 65535.f + 0.5f);
        uint2 d;
        d.x = (unsigned)row | ((unsigned)ia << 17) | ((unsigned)ib << 18)
            | ((unsigned)(col & 127) << 20);
        d.y = qa | (qb << 16);
        edata[gb[b] + (q - loff[b])] = d;
    }
}

// ---------------------------------------------------------------------------
// Per-bucket counting sort by node only (128 keys). Output record:
// {row*64 | ia<<30 | ib<<31, wa1_bf16 | wb1_bf16<<16}; ncnt plain int.
// ---------------------------------------------------------------------------
__global__ __launch_bounds__(256) void bsort_kernel(const int* __restrict__ bstart,
                                                    uint2* __restrict__ edata,
                                                    int* __restrict__ nstart,
                                                    int* __restrict__ ncnt) {
    __shared__ uint2 buf[MAXB];   // 38.4 KB
    __shared__ int h[BNODES];
    __shared__ int cur[BNODES];
    __shared__ int tp[256];
    int tid = threadIdx.x;
    int b = blockIdx.x;
    int e0 = bstart[b], e1 = bstart[b + 1];
    int sz = min(e1 - e0, MAXB);

    if (tid < BNODES) h[tid] = 0;
    for (int j = tid; j < sz; j += 256) buf[j] = edata[e0 + j];
    __syncthreads();
    for (int j = tid; j < sz; j += 256)
        atomicAdd(&h[(buf[j].x >> 20) & 127], 1);
    __syncthreads();
    int v = (tid < BNODES) ? h[tid] : 0;
    tp[tid] = v;
    __syncthreads();
    for (int d = 1; d < 256; d <<= 1) {
        int u = (tid >= d) ? tp[tid - d] : 0;
        __syncthreads();
        tp[tid] += u;
        __syncthreads();
    }
    int excl = tp[tid] - v;
    if (tid < BNODES) {
        cur[tid] = excl;
        int n = b * BNODES + tid;
        if (n < N_NODES) { nstart[n] = e0 + excl; ncnt[n] = v; }
    }
    __syncthreads();
    for (int j = tid; j < sz; j += 256) {
        uint2 r = buf[j];
        unsigned xx = r.x;
        int key = (xx >> 20) & 127;
        int p = atomicAdd(&cur[key], 1);
        float wa1f = (float)(r.y & 0xFFFF) * (1.f / 65535.f);
        float wb1f = (float)(r.y >> 16) * (1.f / 65535.f);
        unsigned wa1b = __float_as_uint(wa1f) >> 16;
        unsigned wb1b = __float_as_uint(wb1f) >> 16;
        uint2 outr;
        outr.x = ((xx & 0x1FFFF) << 6)               // row * 64 bytes
               | ((xx & (1u << 17)) << 13)           // ia -> bit 30
               | ((xx & (1u << 18)) << 13);          // ib -> bit 31
        outr.y = wa1b | (wb1b << 16);
        edata[e0 + p] = outr;
    }
}

// ---------------------------------------------------------------------------
// Fused gather via MFMA: per node, K-loop over 32-edge groups.
// A = coeff tile [16 planes][32 edges] (LDS, wave-private, planes 9-15 = 0),
// B = X^T tile [32 ch][32 edges] (LDS, wave-private), D[plane][ch] in AGPRs.
// Then Z -> zlds rows, and the verified 16x320x32 output MFMA phase.
// ---------------------------------------------------------------------------
__global__ __launch_bounds__(256, 6) void gather_mm_kernel(const bf16* __restrict__ xb,
                                                           const bf16* __restrict__ Bg,
                                                           const float* __restrict__ rb,
                                                           const int* __restrict__ nstart,
                                                           const int* __restrict__ ncnt,
                                                           const uint2* __restrict__ edata,
                                                           float* __restrict__ out) {
    __shared__ __align__(16) bf16 zlds[16 * RS];       // 10496 B
    __shared__ __align__(16) bf16 coef[4][16 * 40];    // 4 x 1280 B (stride 80 B)
    __shared__ __align__(16) bf16 xt[4][32 * 36];      // 4 x 2304 B (stride 72 B)
    int tid = threadIdx.x;
    int wid = tid >> 6;
    int lane = tid & 63;
    int lr = lane & 15, lg = lane >> 4;
    int e31 = lane & 31;
    int n0 = blockIdx.x * 16;
    const char* xbb = (const char*)xb;

    bf16* coefW = coef[wid];
    u16* xtU = (u16*)xt[wid];

    {   // zero coeff tile once (planes 9-15 + pad cols stay 0 forever)
        int* cz = (int*)coefW;
        for (int j = lane; j < 16 * 40 / 2; j += 64) cz[j] = 0;
    }

    for (int s = 0; s < 4; ++s) {
        int rr = wid * 4 + s;
        int n = n0 + rr;
        int s0 = nstart[n];
        int dg = ncnt[n];
        f32x4 accL = {0.f, 0.f, 0.f, 0.f};
        f32x4 accH = {0.f, 0.f, 0.f, 0.f};
        int ng = (dg + 31) >> 5;

        for (int g = 0; g < ng; ++g) {
            uint2 rec = edata[s0 + g * 32 + e31];     // lanes 32-63 duplicate
            bool valid = (g * 32 + e31) < dg;
            float wa1 = __uint_as_float(rec.y << 16);
            float wb1 = __uint_as_float(rec.y & 0xFFFF0000u);
            wa1 = valid ? wa1 : 0.f;                  // NaN-safe
            wb1 = valid ? wb1 : 0.f;
            float wa0 = 1.f - wa1, wb0 = 1.f - wb1;
            unsigned rx = rec.x;
            int ia = (rx >> 30) & 1;
            int ib = (rx >> 31) & 1;
            float A0 = ia ? 0.f : wa0, A1 = ia ? wa0 : wa1, A2 = ia ? wa1 : 0.f;
            float B0 = ib ? 0.f : wb0, B1 = ib ? wb0 : wb1, B2 = ib ? wb1 : 0.f;
            A0 = valid ? A0 : 0.f;                    // zero-coeff for pad edges
            A1 = valid ? A1 : 0.f;
            A2 = valid ? A2 : 0.f;
            int ro = valid ? (int)(rx & 0x00FFFFC0u) : 0;  // clamp pad to row 0

            if (lane < 32) {                          // A tile [plane][edge]
                coefW[0 * 40 + e31] = __float2bfloat16(A0 * B0);
                coefW[1 * 40 + e31] = __float2bfloat16(A0 * B1);
                coefW[2 * 40 + e31] = __float2bfloat16(A0 * B2);
                coefW[3 * 40 + e31] = __float2bfloat16(A1 * B0);
                coefW[4 * 40 + e31] = __float2bfloat16(A1 * B1);
                coefW[5 * 40 + e31] = __float2bfloat16(A1 * B2);
                coefW[6 * 40 + e31] = __float2bfloat16(A2 * B0);
                coefW[7 * 40 + e31] = __float2bfloat16(A2 * B1);
                coefW[8 * 40 + e31] = __float2bfloat16(A2 * B2);
            }

            int rem = dg - g * 32;
#pragma unroll
            for (int t = 0; t < 2; ++t) {             // stage 32 x-rows -> X^T
                int e = 16 * t + (lane >> 2);
                int roe = __shfl(ro, e);
                uint4 v = *(const uint4*)(xbb + roe + (lane & 3) * 16);
                bool vx = e < rem;
                v.x = vx ? v.x : 0u;                  // NaN-safe pad rows
                v.y = vx ? v.y : 0u;
                v.z = vx ? v.z : 0u;
                v.w = vx ? v.w : 0u;
                int c0 = (lane & 3) * 8;
                xtU[(c0 + 0) * 36 + e] = (u16)(v.x);
                xtU[(c0 + 1) * 36 + e] = (u16)(v.x >> 16);
                xtU[(c0 + 2) * 36 + e] = (u16)(v.y);
                xtU[(c0 + 3) * 36 + e] = (u16)(v.y >> 16);
                xtU[(c0 + 4) * 36 + e] = (u16)(v.z);
                xtU[(c0 + 5) * 36 + e] = (u16)(v.z >> 16);
                xtU[(c0 + 6) * 36 + e] = (u16)(v.w);
                xtU[(c0 + 7) * 36 + e] = (u16)(v.w >> 16);
            }

            // A-frag: lane(row=lr plane, k=8*lg+j) -> contiguous 16B
            bf16x8 af = *(const bf16x8*)(coefW + lr * 40 + lg * 8);
            // B-frags: lane(col=ch, k=8*lg+j) from X^T rows ch / ch+16
            const uint2* xlo = (const uint2*)((const char*)xtU + lr * 72 + lg * 16);
            const uint2* xhi = (const uint2*)((const char*)xtU + (lr + 16) * 72 + lg * 16);
            uint2 l0 = xlo[0], l1 = xlo[1];
            uint2 h0 = xhi[0], h1 = xhi[1];
            union UB { unsigned w[4]; bf16x8 v; } bl, bh;
            bl.w[0] = l0.x; bl.w[1] = l0.y; bl.w[2] = l1.x; bl.w[3] = l1.y;
            bh.w[0] = h0.x; bh.w[1] = h0.y; bh.w[2] = h1.x; bh.w[3] = h1.y;
            accL = __builtin_amdgcn_mfma_f32_16x16x32_bf16(af, bl.v, accL, 0, 0, 0);
            accH = __builtin_amdgcn_mfma_f32_16x16x32_bf16(af, bh.v, accH, 0, 0, 0);
        }

        float inv = 1.f / fmaxf((float)dg, 1.f);
#pragma unroll
        for (int r = 0; r < 4; ++r) {                 // C: col=lr, row=lg*4+r
            int p = lg * 4 + r;
            if (p < 9) {
                zlds[rr * RS + p * 32 + lr]      = __float2bfloat16(accL[r] * inv);
                zlds[rr * RS + p * 32 + lr + 16] = __float2bfloat16(accH[r] * inv);
            }
        }
        if (lane < CH) zlds[rr * RS + 288 + lane] = xb[(size_t)n * CH + lane];
    }
    __syncthreads();

    if (wid < 2) {   // wave 0 -> cols 0-15, wave 1 -> cols 16-31
        const bf16* brow = Bg + (size_t)(lr + wid * 16) * RS;
        f32x4 acc = {0.f, 0.f, 0.f, 0.f};
#pragma unroll
        for (int ks = 0; ks < 10; ++ks) {
            int kk = ks * 32 + lg * 8;
            bf16x8 a = *(const bf16x8*)(zlds + lr * RS + kk);
            bf16x8 b = *(const bf16x8*)(brow + kk);        // global, L2-hot
            acc = __builtin_amdgcn_mfma_f32_16x16x32_bf16(a, b, acc, 0, 0, 0);
        }
        float bias = rb[lr + wid * 16];
#pragma unroll
        for (int r = 0; r < 4; ++r) {
            int n = n0 + lg * 4 + r;
            out[(size_t)n * CH + lr + wid * 16] = acc[r] + bias;
        }
    }
}

// ---------------------------------------------------------------------------
extern "C" void kernel_launch(void* const* d_in, const int* in_sizes, int n_in,
                              void* d_out, int out_size, void* d_ws, size_t ws_size,
                              hipStream_t stream) {
    const float* x      = (const float*)d_in[0];
    const float* pseudo = (const float*)d_in[1];
    const float* weight = (const float*)d_in[2];
    const float* root_w = (const float*)d_in[3];
    const float* root_b = (const float*)d_in[4];
    const int*   ei     = (const int*)d_in[5];
    float* out = (float*)d_out;

    int* hist    = (int*)d_ws;                  // 1024 (NBUCK=782 used)
    int* bstart  = hist + 1024;                 // 1024 (NBUCK+1 used)
    int* cursor  = bstart + 1024;               // NBUCK*16 = 12512 (pad 12544)
    int* nstart  = cursor + 12544;              // 100032
    int* ncnt    = nstart + 100032;             // 100032
    char* basep  = (char*)(ncnt + 100032);
    size_t off   = ((size_t)(basep - (char*)d_ws) + 1023) & ~(size_t)1023;
    uint2* edata = (uint2*)((char*)d_ws + off);      // 25.6 MB (+64 record pad)
    bf16* xb     = (bf16*)(edata + N_EDGES + 64);    // 6.4 MB
    bf16* Bg     = xb + (size_t)N_NODES * CH;        // 21 KB

    hipMemsetAsync(hist, 0, NBUCK * sizeof(int), stream);
    prep_kernel<<<(N_NODES * CH / 4 + 255) / 256, 256, 0, stream>>>(x, weight, root_w, xb, Bg);
    bhist_kernel<<<256, 256, 0, stream>>>(ei + N_EDGES, hist);
    bscan_kernel<<<1, 1024, 0, stream>>>(hist, bstart, cursor);
    place_kernel<<<NCHUNK, 1024, 0, stream>>>(pseudo, ei, cursor, edata);
    bsort_kernel<<<NBUCK, 256, 0, stream>>>(bstart, edata, nstart, ncnt);
    gather_mm_kernel<<<N_NODES / 16, 256, 0, stream>>>(xb, Bg, root_b, nstart, ncnt,
                                                       edata, out);
}

// Round 16
// 158.231 us; speedup vs baseline: 1.2528x; 1.2528x over previous
//
#include <hip/hip_runtime.h>
#include <hip/hip_bf16.h>

#define N_NODES 100000
#define N_EDGES 3200000
#define CH 32
#define NK 9
#define KTOT 320                                // 288 z + 32 x (root plane)
#define RS 328                                  // padded K stride (bf16) for zlds

#define BNODES 128                              // destination nodes per bucket
#define NBUCK ((N_NODES + BNODES - 1) / BNODES) // 782
#define CURS_PAD 16
#define MAXB 4800                               // mean 4096, wide margin
#define CHE 8192
#define NCHUNK ((N_EDGES + CHE - 1) / CHE)      // 391

typedef __hip_bfloat16 bf16;
typedef unsigned short u16;
typedef __attribute__((ext_vector_type(8))) short bf16x8;
typedef __attribute__((ext_vector_type(4))) float f32x4;

// ---------------------------------------------------------------------------
// Prep: x -> bf16 copy; [weight | root_w^T] -> bf16 B-matrix (MFMA row layout)
// ---------------------------------------------------------------------------
__global__ __launch_bounds__(256) void prep_kernel(const float* __restrict__ x,
                                                   const float* __restrict__ w,
                                                   const float* __restrict__ rw,
                                                   bf16* __restrict__ xb,
                                                   bf16* __restrict__ Bg) {
    int idx = blockIdx.x * 256 + threadIdx.x;
    if (idx < N_NODES * CH / 4) {
        float4 v = ((const float4*)x)[idx];
        union { bf16 h[4]; uint2 u; } pk;
        pk.h[0] = __float2bfloat16(v.x);
        pk.h[1] = __float2bfloat16(v.y);
        pk.h[2] = __float2bfloat16(v.z);
        pk.h[3] = __float2bfloat16(v.w);
        ((uint2*)xb)[idx] = pk.u;
    }
    if (idx < NK * CH * CH) {           // w flat = [k][i][o] = kk*32 + o
        int kk = idx >> 5, o = idx & 31;
        Bg[o * RS + kk] = __float2bfloat16(w[idx]);
    }
    if (idx < CH * CH) {                // rw[o][i]
        int o = idx >> 5, i = idx & 31;
        Bg[o * RS + 288 + i] = __float2bfloat16(rw[idx]);
    }
}

// ---------------------------------------------------------------------------
// Bucket histogram (global), int4-vectorized
// ---------------------------------------------------------------------------
__global__ __launch_bounds__(256) void bhist_kernel(const int* __restrict__ ei_col,
                                                    int* __restrict__ hist) {
    __shared__ int h[NBUCK];
    for (int j = threadIdx.x; j < NBUCK; j += 256) h[j] = 0;
    __syncthreads();
    const int4* c4 = (const int4*)ei_col;
    int stride = gridDim.x * 256;
    for (int e = blockIdx.x * 256 + threadIdx.x; e < N_EDGES / 4; e += stride) {
        int4 v = c4[e];
        atomicAdd(&h[v.x >> 7], 1);
        atomicAdd(&h[v.y >> 7], 1);
        atomicAdd(&h[v.z >> 7], 1);
        atomicAdd(&h[v.w >> 7], 1);
    }
    __syncthreads();
    for (int j = threadIdx.x; j < NBUCK; j += 256)
        if (h[j]) atomicAdd(&hist[j], h[j]);
}

// ---------------------------------------------------------------------------
// Single-block exclusive scan over buckets; writes bstart + sentinel + cursors
// ---------------------------------------------------------------------------
__global__ __launch_bounds__(1024) void bscan_kernel(const int* __restrict__ hist,
                                                     int* __restrict__ bstart,
                                                     int* __restrict__ cursor) {
    __shared__ int s[1024];
    int t = threadIdx.x;
    int a = (2 * t < NBUCK) ? hist[2 * t] : 0;
    int b = (2 * t + 1 < NBUCK) ? hist[2 * t + 1] : 0;
    s[t] = a + b;
    __syncthreads();
    for (int off = 1; off < 1024; off <<= 1) {
        int u = (t >= off) ? s[t - off] : 0;
        __syncthreads();
        s[t] += u;
        __syncthreads();
    }
    int excl = s[t] - (a + b);
    if (2 * t < NBUCK) {
        bstart[2 * t] = excl;
        cursor[2 * t * CURS_PAD] = excl;
    }
    if (2 * t + 1 < NBUCK) {
        bstart[2 * t + 1] = excl + a;
        cursor[(2 * t + 1) * CURS_PAD] = excl + a;
    }
    if (t == 1023) bstart[NBUCK] = s[1023];
}

// ---------------------------------------------------------------------------
// Place, LDS-staged radix style:
//  A: build records once (sequential reads) into LDS buf + bucket histogram
//  B: local scan + one global batch-alloc atomic per bucket
//  C: slot permutation inv[p] = e_local | b<<13 (cols re-read sequential, L2-hot)
//  D: walk slots in order, read buf from LDS, COALESCED global write.
// No permuted global reads; each edata line written by one wave burst.
// ---------------------------------------------------------------------------
__global__ __launch_bounds__(1024) void place_kernel(const float* __restrict__ pseudo,
                                                     const int* __restrict__ ei,
                                                     int* __restrict__ cursor,
                                                     uint2* __restrict__ edata) {
    __shared__ uint2 buf[CHE];      // 64 KB records
    __shared__ unsigned inv[CHE];   // 32 KB slot -> (e_local | b<<13)
    __shared__ int h[NBUCK];
    __shared__ int loff[NBUCK];
    __shared__ int gb[NBUCK];
    __shared__ int cur[NBUCK];
    __shared__ int tps[1024];
    int tid = threadIdx.x;
    int c0 = blockIdx.x * CHE;
    int cend = min(c0 + CHE, N_EDGES);
    int sz = cend - c0;

    for (int j = tid; j < NBUCK; j += 1024) h[j] = 0;
    __syncthreads();
    // Phase A: build records sequentially
    for (int e = c0 + tid; e < cend; e += 1024) {
        int col = ei[N_EDGES + e];
        int row = ei[e];
        float2 pp = ((const float2*)pseudo)[e];
        float pa = fminf(fmaxf(pp.x, 0.f), 1.f);
        float pb = fminf(fmaxf(pp.y, 0.f), 1.f);
        int ia = pa < 0.5f ? 0 : 1;
        int ib = pb < 0.5f ? 0 : 1;
        float wa1 = 2.f * (pa - 0.5f * (float)ia);
        float wb1 = 2.f * (pb - 0.5f * (float)ib);
        unsigned qa = (unsigned)(wa1 * 65535.f + 0.5f);
        unsigned qb = (unsigned)(wb1 * 65535.f + 0.5f);
        uint2 d;
        d.x = (unsigned)row | ((unsigned)ia << 17) | ((unsigned)ib << 18)
            | ((unsigned)(col & 127) << 20);
        d.y = qa | (qb << 16);
        buf[e - c0] = d;
        atomicAdd(&h[col >> 7], 1);
    }
    __syncthreads();
    // Phase B: local scan + global batch alloc
    int v = (tid < NBUCK) ? h[tid] : 0;
    tps[tid] = v;
    __syncthreads();
    for (int d = 1; d < 1024; d <<= 1) {
        int u = (tid >= d) ? tps[tid - d] : 0;
        __syncthreads();
        tps[tid] += u;
        __syncthreads();
    }
    if (tid < NBUCK) {
        int excl = tps[tid] - v;
        loff[tid] = excl;
        cur[tid] = excl;
        gb[tid] = v ? atomicAdd(&cursor[tid * CURS_PAD], v) : 0;
    }
    __syncthreads();
    // Phase C: slot permutation (cols sequential, L2-hot from phase A)
    for (int e = c0 + tid; e < cend; e += 1024) {
        int b = ei[N_EDGES + e] >> 7;
        int p = atomicAdd(&cur[b], 1);
        inv[p] = (unsigned)(e - c0) | ((unsigned)b << 13);
    }
    __syncthreads();
    // Phase D: coalesced write-out from LDS
    for (int q = tid; q < sz; q += 1024) {
        unsigned u = inv[q];
        int b = (int)(u >> 13);
        uint2 rec = buf[u & 8191];
        edata[gb[b] + (q - loff[b])] = rec;
    }
}

// ---------------------------------------------------------------------------
// Per-bucket counting sort by node only (128 keys). Output record:
// {row*64 | ia<<30 | ib<<31, wa1_bf16 | wb1_bf16<<16}; ncnt plain int.
// ---------------------------------------------------------------------------
__global__ __launch_bounds__(256) void bsort_kernel(const int* __restrict__ bstart,
                                                    uint2* __restrict__ edata,
                                                    int* __restrict__ nstart,
                                                    int* __restrict__ ncnt) {
    __shared__ uint2 buf[MAXB];   // 38.4 KB
    __shared__ int h[BNODES];
    __shared__ int cur[BNODES];
    __shared__ int tp[256];
    int tid = threadIdx.x;
    int b = blockIdx.x;
    int e0 = bstart[b], e1 = bstart[b + 1];
    int sz = min(e1 - e0, MAXB);

    if (tid < BNODES) h[tid] = 0;
    for (int j = tid; j < sz; j += 256) buf[j] = edata[e0 + j];
    __syncthreads();
    for (int j = tid; j < sz; j += 256)
        atomicAdd(&h[(buf[j].x >> 20) & 127], 1);
    __syncthreads();
    int v = (tid < BNODES) ? h[tid] : 0;
    tp[tid] = v;
    __syncthreads();
    for (int d = 1; d < 256; d <<= 1) {
        int u = (tid >= d) ? tp[tid - d] : 0;
        __syncthreads();
        tp[tid] += u;
        __syncthreads();
    }
    int excl = tp[tid] - v;
    if (tid < BNODES) {
        cur[tid] = excl;
        int n = b * BNODES + tid;
        if (n < N_NODES) { nstart[n] = e0 + excl; ncnt[n] = v; }
    }
    __syncthreads();
    for (int j = tid; j < sz; j += 256) {
        uint2 r = buf[j];
        unsigned xx = r.x;
        int key = (xx >> 20) & 127;
        int p = atomicAdd(&cur[key], 1);
        float wa1f = (float)(r.y & 0xFFFF) * (1.f / 65535.f);
        float wb1f = (float)(r.y >> 16) * (1.f / 65535.f);
        unsigned wa1b = __float_as_uint(wa1f) >> 16;
        unsigned wb1b = __float_as_uint(wb1f) >> 16;
        uint2 outr;
        outr.x = ((xx & 0x1FFFF) << 6)               // row * 64 bytes
               | ((xx & (1u << 17)) << 13)           // ia -> bit 30
               | ((xx & (1u << 18)) << 13);          // ib -> bit 31
        outr.y = wa1b | (wb1b << 16);
        edata[e0 + p] = outr;
    }
}

// ---------------------------------------------------------------------------
// Fused gather via MFMA: per node, K-loop over 32-edge groups.
// A = coeff tile [16 planes][32 edges] (LDS, wave-private, planes 9-15 = 0),
// B = X^T tile [32 ch][32 edges] (LDS, wave-private), D[plane][ch] in AGPRs.
// Then Z -> zlds rows, and the verified 16x320x32 output MFMA phase.
// ---------------------------------------------------------------------------
__global__ __launch_bounds__(256, 6) void gather_mm_kernel(const bf16* __restrict__ xb,
                                                           const bf16* __restrict__ Bg,
                                                           const float* __restrict__ rb,
                                                           const int* __restrict__ nstart,
                                                           const int* __restrict__ ncnt,
                                                           const uint2* __restrict__ edata,
                                                           float* __restrict__ out) {
    __shared__ __align__(16) bf16 zlds[16 * RS];       // 10496 B
    __shared__ __align__(16) bf16 coef[4][16 * 40];    // 4 x 1280 B (stride 80 B)
    __shared__ __align__(16) bf16 xt[4][32 * 36];      // 4 x 2304 B (stride 72 B)
    int tid = threadIdx.x;
    int wid = tid >> 6;
    int lane = tid & 63;
    int lr = lane & 15, lg = lane >> 4;
    int e31 = lane & 31;
    int n0 = blockIdx.x * 16;
    const char* xbb = (const char*)xb;

    bf16* coefW = coef[wid];
    u16* xtU = (u16*)xt[wid];

    {   // zero coeff tile once (planes 9-15 + pad cols stay 0 forever)
        int* cz = (int*)coefW;
        for (int j = lane; j < 16 * 40 / 2; j += 64) cz[j] = 0;
    }

    for (int s = 0; s < 4; ++s) {
        int rr = wid * 4 + s;
        int n = n0 + rr;
        int s0 = nstart[n];
        int dg = ncnt[n];
        f32x4 accL = {0.f, 0.f, 0.f, 0.f};
        f32x4 accH = {0.f, 0.f, 0.f, 0.f};
        int ng = (dg + 31) >> 5;

        for (int g = 0; g < ng; ++g) {
            uint2 rec = edata[s0 + g * 32 + e31];     // lanes 32-63 duplicate
            bool valid = (g * 32 + e31) < dg;
            float wa1 = __uint_as_float(rec.y << 16);
            float wb1 = __uint_as_float(rec.y & 0xFFFF0000u);
            wa1 = valid ? wa1 : 0.f;                  // NaN-safe
            wb1 = valid ? wb1 : 0.f;
            float wa0 = 1.f - wa1, wb0 = 1.f - wb1;
            unsigned rx = rec.x;
            int ia = (rx >> 30) & 1;
            int ib = (rx >> 31) & 1;
            float A0 = ia ? 0.f : wa0, A1 = ia ? wa0 : wa1, A2 = ia ? wa1 : 0.f;
            float B0 = ib ? 0.f : wb0, B1 = ib ? wb0 : wb1, B2 = ib ? wb1 : 0.f;
            A0 = valid ? A0 : 0.f;                    // zero-coeff for pad edges
            A1 = valid ? A1 : 0.f;
            A2 = valid ? A2 : 0.f;
            int ro = valid ? (int)(rx & 0x00FFFFC0u) : 0;  // clamp pad to row 0

            if (lane < 32) {                          // A tile [plane][edge]
                coefW[0 * 40 + e31] = __float2bfloat16(A0 * B0);
                coefW[1 * 40 + e31] = __float2bfloat16(A0 * B1);
                coefW[2 * 40 + e31] = __float2bfloat16(A0 * B2);
                coefW[3 * 40 + e31] = __float2bfloat16(A1 * B0);
                coefW[4 * 40 + e31] = __float2bfloat16(A1 * B1);
                coefW[5 * 40 + e31] = __float2bfloat16(A1 * B2);
                coefW[6 * 40 + e31] = __float2bfloat16(A2 * B0);
                coefW[7 * 40 + e31] = __float2bfloat16(A2 * B1);
                coefW[8 * 40 + e31] = __float2bfloat16(A2 * B2);
            }

            int rem = dg - g * 32;
#pragma unroll
            for (int t = 0; t < 2; ++t) {             // stage 32 x-rows -> X^T
                int e = 16 * t + (lane >> 2);
                int roe = __shfl(ro, e);
                uint4 v = *(const uint4*)(xbb + roe + (lane & 3) * 16);
                bool vx = e < rem;
                v.x = vx ? v.x : 0u;                  // NaN-safe pad rows
                v.y = vx ? v.y : 0u;
                v.z = vx ? v.z : 0u;
                v.w = vx ? v.w : 0u;
                int c0 = (lane & 3) * 8;
                xtU[(c0 + 0) * 36 + e] = (u16)(v.x);
                xtU[(c0 + 1) * 36 + e] = (u16)(v.x >> 16);
                xtU[(c0 + 2) * 36 + e] = (u16)(v.y);
                xtU[(c0 + 3) * 36 + e] = (u16)(v.y >> 16);
                xtU[(c0 + 4) * 36 + e] = (u16)(v.z);
                xtU[(c0 + 5) * 36 + e] = (u16)(v.z >> 16);
                xtU[(c0 + 6) * 36 + e] = (u16)(v.w);
                xtU[(c0 + 7) * 36 + e] = (u16)(v.w >> 16);
            }

            // A-frag: lane(row=lr plane, k=8*lg+j) -> contiguous 16B
            bf16x8 af = *(const bf16x8*)(coefW + lr * 40 + lg * 8);
            // B-frags: lane(col=ch, k=8*lg+j) from X^T rows ch / ch+16
            const uint2* xlo = (const uint2*)((const char*)xtU + lr * 72 + lg * 16);
            const uint2* xhi = (const uint2*)((const char*)xtU + (lr + 16) * 72 + lg * 16);
            uint2 l0 = xlo[0], l1 = xlo[1];
            uint2 h0 = xhi[0], h1 = xhi[1];
            union UB { unsigned w[4]; bf16x8 v; } bl, bh;
            bl.w[0] = l0.x; bl.w[1] = l0.y; bl.w[2] = l1.x; bl.w[3] = l1.y;
            bh.w[0] = h0.x; bh.w[1] = h0.y; bh.w[2] = h1.x; bh.w[3] = h1.y;
            accL = __builtin_amdgcn_mfma_f32_16x16x32_bf16(af, bl.v, accL, 0, 0, 0);
            accH = __builtin_amdgcn_mfma_f32_16x16x32_bf16(af, bh.v, accH, 0, 0, 0);
        }

        float inv = 1.f / fmaxf((float)dg, 1.f);
#pragma unroll
        for (int r = 0; r < 4; ++r) {                 // C: col=lr, row=lg*4+r
            int p = lg * 4 + r;
            if (p < 9) {
                zlds[rr * RS + p * 32 + lr]      = __float2bfloat16(accL[r] * inv);
                zlds[rr * RS + p * 32 + lr + 16] = __float2bfloat16(accH[r] * inv);
            }
        }
        if (lane < CH) zlds[rr * RS + 288 + lane] = xb[(size_t)n * CH + lane];
    }
    __syncthreads();

    if (wid < 2) {   // wave 0 -> cols 0-15, wave 1 -> cols 16-31
        const bf16* brow = Bg + (size_t)(lr + wid * 16) * RS;
        f32x4 acc = {0.f, 0.f, 0.f, 0.f};
#pragma unroll
        for (int ks = 0; ks < 10; ++ks) {
            int kk = ks * 32 + lg * 8;
            bf16x8 a = *(const bf16x8*)(zlds + lr * RS + kk);
            bf16x8 b = *(const bf16x8*)(brow + kk);        // global, L2-hot
            acc = __builtin_amdgcn_mfma_f32_16x16x32_bf16(a, b, acc, 0, 0, 0);
        }
        float bias = rb[lr + wid * 16];
#pragma unroll
        for (int r = 0; r < 4; ++r) {
            int n = n0 + lg * 4 + r;
            out[(size_t)n * CH + lr + wid * 16] = acc[r] + bias;
        }
    }
}

// ---------------------------------------------------------------------------
extern "C" void kernel_launch(void* const* d_in, const int* in_sizes, int n_in,
                              void* d_out, int out_size, void* d_ws, size_t ws_size,
                              hipStream_t stream) {
    const float* x      = (const float*)d_in[0];
    const float* pseudo = (const float*)d_in[1];
    const float* weight = (const float*)d_in[2];
    const float* root_w = (const float*)d_in[3];
    const float* root_b = (const float*)d_in[4];
    const int*   ei     = (const int*)d_in[5];
    float* out = (float*)d_out;

    int* hist    = (int*)d_ws;                  // 1024 (NBUCK=782 used)
    int* bstart  = hist + 1024;                 // 1024 (NBUCK+1 used)
    int* cursor  = bstart + 1024;               // NBUCK*16 = 12512 (pad 12544)
    int* nstart  = cursor + 12544;              // 100032
    int* ncnt    = nstart + 100032;             // 100032
    char* basep  = (char*)(ncnt + 100032);
    size_t off   = ((size_t)(basep - (char*)d_ws) + 1023) & ~(size_t)1023;
    uint2* edata = (uint2*)((char*)d_ws + off);      // 25.6 MB (+64 record pad)
    bf16* xb     = (bf16*)(edata + N_EDGES + 64);    // 6.4 MB
    bf16* Bg     = xb + (size_t)N_NODES * CH;        // 21 KB

    hipMemsetAsync(hist, 0, NBUCK * sizeof(int), stream);
    prep_kernel<<<(N_NODES * CH / 4 + 255) / 256, 256, 0, stream>>>(x, weight, root_w, xb, Bg);
    bhist_kernel<<<256, 256, 0, stream>>>(ei + N_EDGES, hist);
    bscan_kernel<<<1, 1024, 0, stream>>>(hist, bstart, cursor);
    place_kernel<<<NCHUNK, 1024, 0, stream>>>(pseudo, ei, cursor, edata);
    bsort_kernel<<<NBUCK, 256, 0, stream>>>(bstart, edata, nstart, ncnt);
    gather_mm_kernel<<<N_NODES / 16, 256, 0, stream>>>(xb, Bg, root_b, nstart, ncnt,
                                                       edata, out);
}

// Round 17
// 155.501 us; speedup vs baseline: 1.2748x; 1.0176x over previous
//
#include <hip/hip_runtime.h>
#include <hip/hip_bf16.h>

#define N_NODES 100000
#define N_EDGES 3200000
#define CH 32
#define NK 9
#define KTOT 320                                // 288 z + 32 x (root plane)
#define RS 328                                  // padded K stride (bf16) for zlds

#define BNODES 128                              // destination nodes per bucket
#define NBUCK ((N_NODES + BNODES - 1) / BNODES) // 782
#define CURS_PAD 16
#define MAXB 4800                               // mean 4096, wide margin
#define CHE 8192
#define NCHUNK ((N_EDGES + CHE - 1) / CHE)      // 391

typedef __hip_bfloat16 bf16;
typedef unsigned short u16;
typedef __attribute__((ext_vector_type(8))) short bf16x8;
typedef __attribute__((ext_vector_type(4))) float f32x4;

// ---------------------------------------------------------------------------
// Prep: x -> bf16 copy; [weight | root_w^T] -> bf16 B-matrix (MFMA row layout)
// ---------------------------------------------------------------------------
__global__ __launch_bounds__(256) void prep_kernel(const float* __restrict__ x,
                                                   const float* __restrict__ w,
                                                   const float* __restrict__ rw,
                                                   bf16* __restrict__ xb,
                                                   bf16* __restrict__ Bg) {
    int idx = blockIdx.x * 256 + threadIdx.x;
    if (idx < N_NODES * CH / 4) {
        float4 v = ((const float4*)x)[idx];
        union { bf16 h[4]; uint2 u; } pk;
        pk.h[0] = __float2bfloat16(v.x);
        pk.h[1] = __float2bfloat16(v.y);
        pk.h[2] = __float2bfloat16(v.z);
        pk.h[3] = __float2bfloat16(v.w);
        ((uint2*)xb)[idx] = pk.u;
    }
    if (idx < NK * CH * CH) {           // w flat = [k][i][o] = kk*32 + o
        int kk = idx >> 5, o = idx & 31;
        Bg[o * RS + kk] = __float2bfloat16(w[idx]);
    }
    if (idx < CH * CH) {                // rw[o][i]
        int o = idx >> 5, i = idx & 31;
        Bg[o * RS + 288 + i] = __float2bfloat16(rw[idx]);
    }
}

// ---------------------------------------------------------------------------
// Bucket histogram (global), int4-vectorized
// ---------------------------------------------------------------------------
__global__ __launch_bounds__(256) void bhist_kernel(const int* __restrict__ ei_col,
                                                    int* __restrict__ hist) {
    __shared__ int h[NBUCK];
    for (int j = threadIdx.x; j < NBUCK; j += 256) h[j] = 0;
    __syncthreads();
    const int4* c4 = (const int4*)ei_col;
    int stride = gridDim.x * 256;
    for (int e = blockIdx.x * 256 + threadIdx.x; e < N_EDGES / 4; e += stride) {
        int4 v = c4[e];
        atomicAdd(&h[v.x >> 7], 1);
        atomicAdd(&h[v.y >> 7], 1);
        atomicAdd(&h[v.z >> 7], 1);
        atomicAdd(&h[v.w >> 7], 1);
    }
    __syncthreads();
    for (int j = threadIdx.x; j < NBUCK; j += 256)
        if (h[j]) atomicAdd(&hist[j], h[j]);
}

// ---------------------------------------------------------------------------
// Single-block exclusive scan over buckets; writes bstart + sentinel + cursors
// ---------------------------------------------------------------------------
__global__ __launch_bounds__(1024) void bscan_kernel(const int* __restrict__ hist,
                                                     int* __restrict__ bstart,
                                                     int* __restrict__ cursor) {
    __shared__ int s[1024];
    int t = threadIdx.x;
    int a = (2 * t < NBUCK) ? hist[2 * t] : 0;
    int b = (2 * t + 1 < NBUCK) ? hist[2 * t + 1] : 0;
    s[t] = a + b;
    __syncthreads();
    for (int off = 1; off < 1024; off <<= 1) {
        int u = (t >= off) ? s[t - off] : 0;
        __syncthreads();
        s[t] += u;
        __syncthreads();
    }
    int excl = s[t] - (a + b);
    if (2 * t < NBUCK) {
        bstart[2 * t] = excl;
        cursor[2 * t * CURS_PAD] = excl;
    }
    if (2 * t + 1 < NBUCK) {
        bstart[2 * t + 1] = excl + a;
        cursor[(2 * t + 1) * CURS_PAD] = excl + a;
    }
    if (t == 1023) bstart[NBUCK] = s[1023];
}

// ---------------------------------------------------------------------------
// Place, LDS-staged radix style (R16-proven):
//  A: build records once (sequential reads) into LDS buf + bucket histogram
//  B: local scan + one global batch-alloc atomic per bucket
//  C: slot permutation inv[p] = e_local | b<<13 (cols re-read sequential)
//  D: walk slots in order, read buf from LDS, COALESCED global write.
// ---------------------------------------------------------------------------
__global__ __launch_bounds__(1024) void place_kernel(const float* __restrict__ pseudo,
                                                     const int* __restrict__ ei,
                                                     int* __restrict__ cursor,
                                                     uint2* __restrict__ edata) {
    __shared__ uint2 buf[CHE];      // 64 KB records
    __shared__ unsigned inv[CHE];   // 32 KB slot -> (e_local | b<<13)
    __shared__ int h[NBUCK];
    __shared__ int loff[NBUCK];
    __shared__ int gb[NBUCK];
    __shared__ int cur[NBUCK];
    __shared__ int tps[1024];
    int tid = threadIdx.x;
    int c0 = blockIdx.x * CHE;
    int cend = min(c0 + CHE, N_EDGES);
    int sz = cend - c0;

    for (int j = tid; j < NBUCK; j += 1024) h[j] = 0;
    __syncthreads();
    for (int e = c0 + tid; e < cend; e += 1024) {
        int col = ei[N_EDGES + e];
        int row = ei[e];
        float2 pp = ((const float2*)pseudo)[e];
        float pa = fminf(fmaxf(pp.x, 0.f), 1.f);
        float pb = fminf(fmaxf(pp.y, 0.f), 1.f);
        int ia = pa < 0.5f ? 0 : 1;
        int ib = pb < 0.5f ? 0 : 1;
        float wa1 = 2.f * (pa - 0.5f * (float)ia);
        float wb1 = 2.f * (pb - 0.5f * (float)ib);
        unsigned qa = (unsigned)(wa1 * 65535.f + 0.5f);
        unsigned qb = (unsigned)(wb1 * 65535.f + 0.5f);
        uint2 d;
        d.x = (unsigned)row | ((unsigned)ia << 17) | ((unsigned)ib << 18)
            | ((unsigned)(col & 127) << 20);
        d.y = qa | (qb << 16);
        buf[e - c0] = d;
        atomicAdd(&h[col >> 7], 1);
    }
    __syncthreads();
    int v = (tid < NBUCK) ? h[tid] : 0;
    tps[tid] = v;
    __syncthreads();
    for (int d = 1; d < 1024; d <<= 1) {
        int u = (tid >= d) ? tps[tid - d] : 0;
        __syncthreads();
        tps[tid] += u;
        __syncthreads();
    }
    if (tid < NBUCK) {
        int excl = tps[tid] - v;
        loff[tid] = excl;
        cur[tid] = excl;
        gb[tid] = v ? atomicAdd(&cursor[tid * CURS_PAD], v) : 0;
    }
    __syncthreads();
    for (int e = c0 + tid; e < cend; e += 1024) {
        int b = ei[N_EDGES + e] >> 7;
        int p = atomicAdd(&cur[b], 1);
        inv[p] = (unsigned)(e - c0) | ((unsigned)b << 13);
    }
    __syncthreads();
    for (int q = tid; q < sz; q += 1024) {
        unsigned u = inv[q];
        int b = (int)(u >> 13);
        uint2 rec = buf[u & 8191];
        edata[gb[b] + (q - loff[b])] = rec;
    }
}

// ---------------------------------------------------------------------------
// Per-bucket counting sort by node only (128 keys). Output record:
// {row*64 | ia<<30 | ib<<31, wa1_bf16 | wb1_bf16<<16}; ncnt plain int.
// ---------------------------------------------------------------------------
__global__ __launch_bounds__(256) void bsort_kernel(const int* __restrict__ bstart,
                                                    uint2* __restrict__ edata,
                                                    int* __restrict__ nstart,
                                                    int* __restrict__ ncnt) {
    __shared__ uint2 buf[MAXB];   // 38.4 KB
    __shared__ int h[BNODES];
    __shared__ int cur[BNODES];
    __shared__ int tp[256];
    int tid = threadIdx.x;
    int b = blockIdx.x;
    int e0 = bstart[b], e1 = bstart[b + 1];
    int sz = min(e1 - e0, MAXB);

    if (tid < BNODES) h[tid] = 0;
    for (int j = tid; j < sz; j += 256) buf[j] = edata[e0 + j];
    __syncthreads();
    for (int j = tid; j < sz; j += 256)
        atomicAdd(&h[(buf[j].x >> 20) & 127], 1);
    __syncthreads();
    int v = (tid < BNODES) ? h[tid] : 0;
    tp[tid] = v;
    __syncthreads();
    for (int d = 1; d < 256; d <<= 1) {
        int u = (tid >= d) ? tp[tid - d] : 0;
        __syncthreads();
        tp[tid] += u;
        __syncthreads();
    }
    int excl = tp[tid] - v;
    if (tid < BNODES) {
        cur[tid] = excl;
        int n = b * BNODES + tid;
        if (n < N_NODES) { nstart[n] = e0 + excl; ncnt[n] = v; }
    }
    __syncthreads();
    for (int j = tid; j < sz; j += 256) {
        uint2 r = buf[j];
        unsigned xx = r.x;
        int key = (xx >> 20) & 127;
        int p = atomicAdd(&cur[key], 1);
        float wa1f = (float)(r.y & 0xFFFF) * (1.f / 65535.f);
        float wb1f = (float)(r.y >> 16) * (1.f / 65535.f);
        unsigned wa1b = __float_as_uint(wa1f) >> 16;
        unsigned wb1b = __float_as_uint(wb1f) >> 16;
        uint2 outr;
        outr.x = ((xx & 0x1FFFF) << 6)               // row * 64 bytes
               | ((xx & (1u << 17)) << 13)           // ia -> bit 30
               | ((xx & (1u << 18)) << 13);          // ib -> bit 31
        outr.y = wa1b | (wb1b << 16);
        edata[e0 + p] = outr;
    }
}

// ---------------------------------------------------------------------------
// Fused gather via MFMA. X^T staging now uses lane-paired u32 writes
// (shfl_xor exchange) -> all 32 banks 2-way = conflict-free, 8 stores vs 16.
// Next-group edata record is prefetched (pad-safe) to overlap latency.
// ---------------------------------------------------------------------------
__global__ __launch_bounds__(256, 6) void gather_mm_kernel(const bf16* __restrict__ xb,
                                                           const bf16* __restrict__ Bg,
                                                           const float* __restrict__ rb,
                                                           const int* __restrict__ nstart,
                                                           const int* __restrict__ ncnt,
                                                           const uint2* __restrict__ edata,
                                                           float* __restrict__ out) {
    __shared__ __align__(16) bf16 zlds[16 * RS];       // 10496 B
    __shared__ __align__(16) bf16 coef[4][16 * 40];    // 4 x 1280 B (stride 80 B)
    __shared__ __align__(16) bf16 xt[4][32 * 36];      // 4 x 2304 B (stride 72 B)
    int tid = threadIdx.x;
    int wid = tid >> 6;
    int lane = tid & 63;
    int lr = lane & 15, lg = lane >> 4;
    int e31 = lane & 31;
    int n0 = blockIdx.x * 16;
    const char* xbb = (const char*)xb;
    bool evenlane = (lane & 4) == 0;

    bf16* coefW = coef[wid];
    u16* xtU = (u16*)xt[wid];
    unsigned* x32 = (unsigned*)xt[wid];

    {   // zero coeff tile once (planes 9-15 + pad cols stay 0 forever)
        int* cz = (int*)coefW;
        for (int j = lane; j < 16 * 40 / 2; j += 64) cz[j] = 0;
    }

    for (int s = 0; s < 4; ++s) {
        int rr = wid * 4 + s;
        int n = n0 + rr;
        int s0 = nstart[n];
        int dg = ncnt[n];
        f32x4 accL = {0.f, 0.f, 0.f, 0.f};
        f32x4 accH = {0.f, 0.f, 0.f, 0.f};
        int ng = (dg + 31) >> 5;

        uint2 rec = edata[s0 + e31];                  // group 0 (pad-safe)
        for (int g = 0; g < ng; ++g) {
            uint2 rec_nx = edata[s0 + (g + 1) * 32 + e31];  // prefetch (pad-safe)
            bool valid = (g * 32 + e31) < dg;
            float wa1 = __uint_as_float(rec.y << 16);
            float wb1 = __uint_as_float(rec.y & 0xFFFF0000u);
            wa1 = valid ? wa1 : 0.f;                  // NaN-safe
            wb1 = valid ? wb1 : 0.f;
            float wa0 = 1.f - wa1, wb0 = 1.f - wb1;
            unsigned rx = rec.x;
            int ia = (rx >> 30) & 1;
            int ib = (rx >> 31) & 1;
            float A0 = ia ? 0.f : wa0, A1 = ia ? wa0 : wa1, A2 = ia ? wa1 : 0.f;
            float B0 = ib ? 0.f : wb0, B1 = ib ? wb0 : wb1, B2 = ib ? wb1 : 0.f;
            A0 = valid ? A0 : 0.f;                    // zero-coeff for pad edges
            A1 = valid ? A1 : 0.f;
            A2 = valid ? A2 : 0.f;
            int ro = valid ? (int)(rx & 0x00FFFFC0u) : 0;  // clamp pad to row 0

            if (lane < 32) {                          // A tile [plane][edge]
                coefW[0 * 40 + e31] = __float2bfloat16(A0 * B0);
                coefW[1 * 40 + e31] = __float2bfloat16(A0 * B1);
                coefW[2 * 40 + e31] = __float2bfloat16(A0 * B2);
                coefW[3 * 40 + e31] = __float2bfloat16(A1 * B0);
                coefW[4 * 40 + e31] = __float2bfloat16(A1 * B1);
                coefW[5 * 40 + e31] = __float2bfloat16(A1 * B2);
                coefW[6 * 40 + e31] = __float2bfloat16(A2 * B0);
                coefW[7 * 40 + e31] = __float2bfloat16(A2 * B1);
                coefW[8 * 40 + e31] = __float2bfloat16(A2 * B2);
            }

            int rem = dg - g * 32;
#pragma unroll
            for (int t = 0; t < 2; ++t) {             // stage 32 x-rows -> X^T
                int e = 16 * t + (lane >> 2);
                int roe = __shfl(ro, e);
                uint4 v = *(const uint4*)(xbb + roe + (lane & 3) * 16);
                bool vx = e < rem;
                v.x = vx ? v.x : 0u;                  // NaN-safe pad rows
                v.y = vx ? v.y : 0u;
                v.z = vx ? v.z : 0u;
                v.w = vx ? v.w : 0u;
                // pair (lane, lane^4) = edges (e_even, e_odd); exchange halves
                unsigned s0v = evenlane ? v.z : v.x;
                unsigned s1v = evenlane ? v.w : v.y;
                unsigned r0 = __shfl_xor(s0v, 4);
                unsigned r1 = __shfl_xor(s1v, 4);
                unsigned Ae = evenlane ? v.x : r0;    // even-e, chs a,a+1
                unsigned Bo = evenlane ? r0 : v.z;    // odd-e,  chs a,a+1
                unsigned Ce = evenlane ? v.y : r1;    // even-e, chs a+2,a+3
                unsigned Do = evenlane ? r1 : v.w;    // odd-e,  chs a+2,a+3
                int a = (lane & 3) * 8 + (evenlane ? 0 : 4);
                int sl = 8 * t + (lane >> 3);         // e>>1 (same for pair)
                // u32 = [even-e | odd-e<<16] per channel; banks 2-way = free
                x32[(a + 0) * 18 + sl] = (Ae & 0xFFFFu) | (Bo << 16);
                x32[(a + 1) * 18 + sl] = (Ae >> 16) | (Bo & 0xFFFF0000u);
                x32[(a + 2) * 18 + sl] = (Ce & 0xFFFFu) | (Do << 16);
                x32[(a + 3) * 18 + sl] = (Ce >> 16) | (Do & 0xFFFF0000u);
            }

            // A-frag: lane(row=lr plane, k=8*lg+j) -> contiguous 16B
            bf16x8 af = *(const bf16x8*)(coefW + lr * 40 + lg * 8);
            // B-frags: lane(col=ch, k=8*lg+j) from X^T rows ch / ch+16
            const uint2* xlo = (const uint2*)((const char*)xtU + lr * 72 + lg * 16);
            const uint2* xhi = (const uint2*)((const char*)xtU + (lr + 16) * 72 + lg * 16);
            uint2 l0 = xlo[0], l1 = xlo[1];
            uint2 h0 = xhi[0], h1 = xhi[1];
            union UB { unsigned w[4]; bf16x8 v; } bl, bh;
            bl.w[0] = l0.x; bl.w[1] = l0.y; bl.w[2] = l1.x; bl.w[3] = l1.y;
            bh.w[0] = h0.x; bh.w[1] = h0.y; bh.w[2] = h1.x; bh.w[3] = h1.y;
            accL = __builtin_amdgcn_mfma_f32_16x16x32_bf16(af, bl.v, accL, 0, 0, 0);
            accH = __builtin_amdgcn_mfma_f32_16x16x32_bf16(af, bh.v, accH, 0, 0, 0);
            rec = rec_nx;
        }

        float inv = 1.f / fmaxf((float)dg, 1.f);
#pragma unroll
        for (int r = 0; r < 4; ++r) {                 // C: col=lr, row=lg*4+r
            int p = lg * 4 + r;
            if (p < 9) {
                zlds[rr * RS + p * 32 + lr]      = __float2bfloat16(accL[r] * inv);
                zlds[rr * RS + p * 32 + lr + 16] = __float2bfloat16(accH[r] * inv);
            }
        }
        if (lane < CH) zlds[rr * RS + 288 + lane] = xb[(size_t)n * CH + lane];
    }
    __syncthreads();

    if (wid < 2) {   // wave 0 -> cols 0-15, wave 1 -> cols 16-31
        const bf16* brow = Bg + (size_t)(lr + wid * 16) * RS;
        f32x4 acc = {0.f, 0.f, 0.f, 0.f};
#pragma unroll
        for (int ks = 0; ks < 10; ++ks) {
            int kk = ks * 32 + lg * 8;
            bf16x8 a = *(const bf16x8*)(zlds + lr * RS + kk);
            bf16x8 b = *(const bf16x8*)(brow + kk);        // global, L2-hot
            acc = __builtin_amdgcn_mfma_f32_16x16x32_bf16(a, b, acc, 0, 0, 0);
        }
        float bias = rb[lr + wid * 16];
#pragma unroll
        for (int r = 0; r < 4; ++r) {
            int n = n0 + lg * 4 + r;
            out[(size_t)n * CH + lr + wid * 16] = acc[r] + bias;
        }
    }
}

// ---------------------------------------------------------------------------
extern "C" void kernel_launch(void* const* d_in, const int* in_sizes, int n_in,
                              void* d_out, int out_size, void* d_ws, size_t ws_size,
                              hipStream_t stream) {
    const float* x      = (const float*)d_in[0];
    const float* pseudo = (const float*)d_in[1];
    const float* weight = (const float*)d_in[2];
    const float* root_w = (const float*)d_in[3];
    const float* root_b = (const float*)d_in[4];
    const int*   ei     = (const int*)d_in[5];
    float* out = (float*)d_out;

    int* hist    = (int*)d_ws;                  // 1024 (NBUCK=782 used)
    int* bstart  = hist + 1024;                 // 1024 (NBUCK+1 used)
    int* cursor  = bstart + 1024;               // NBUCK*16 = 12512 (pad 12544)
    int* nstart  = cursor + 12544;              // 100032
    int* ncnt    = nstart + 100032;             // 100032
    char* basep  = (char*)(ncnt + 100032);
    size_t off   = ((size_t)(basep - (char*)d_ws) + 1023) & ~(size_t)1023;
    uint2* edata = (uint2*)((char*)d_ws + off);      // 25.6 MB (+64 record pad)
    bf16* xb     = (bf16*)(edata + N_EDGES + 64);    // 6.4 MB
    bf16* Bg     = xb + (size_t)N_NODES * CH;        // 21 KB

    hipMemsetAsync(hist, 0, NBUCK * sizeof(int), stream);
    prep_kernel<<<(N_NODES * CH / 4 + 255) / 256, 256, 0, stream>>>(x, weight, root_w, xb, Bg);
    bhist_kernel<<<256, 256, 0, stream>>>(ei + N_EDGES, hist);
    bscan_kernel<<<1, 1024, 0, stream>>>(hist, bstart, cursor);
    place_kernel<<<NCHUNK, 1024, 0, stream>>>(pseudo, ei, cursor, edata);
    bsort_kernel<<<NBUCK, 256, 0, stream>>>(bstart, edata, nstart, ncnt);
    gather_mm_kernel<<<N_NODES / 16, 256, 0, stream>>>(xb, Bg, root_b, nstart, ncnt,
                                                       edata, out);
}